// Round 9
// baseline (65.972 us; speedup 1.0000x reference)
//
#include <hip/hip_runtime.h>

// DIAGNOSTIC ROUND 2: R7 (nt-store) kernel repeated 8x internally with a
// bijective per-rep plane permutation (output written 8x with identical
// correct values -> deterministic). Purpose: expose this kernel's own
// FETCH/WRITE/dur in the rocprof top-5 to test whether nt stores suppress
// L3 write-allocation (FETCH/rep -> 0 means x stays L3-resident).
//
// out[n,c,h,w] = sum over valid (i,j) in 3x3 of max(x[n,c,h,w], thr[c,3i+j])
// valid: i=0 iff h<111, i=2 iff h>0; j=0 iff w<111, j=2 iff w>0.

#define WQ 28
#define NH 112
#define PLANE_F4 (NH * WQ)   // 3136
#define TPB 448
#define PER_T 7
#define REPS 8

typedef float f32x4 __attribute__((ext_vector_type(4)));

__global__ __launch_bounds__(TPB) void convblock_ntrep_kernel(
    const float* __restrict__ x, const float* __restrict__ thr,
    float* __restrict__ out) {
  const int tid = threadIdx.x;

  for (int rep = 0; rep < REPS; ++rep) {
    const int plane = (blockIdx.x + rep * 67) & 511;  // bijection per rep
    const int c = plane & 63;

    float t[9];
#pragma unroll
    for (int k = 0; k < 9; ++k) t[k] = thr[c * 9 + k];

    const f32x4* __restrict__ xin =
        reinterpret_cast<const f32x4*>(x) + (size_t)plane * PLANE_F4;
    f32x4* __restrict__ xout =
        reinterpret_cast<f32x4*>(out) + (size_t)plane * PLANE_F4;

    // All 7 loads in flight before any compute.
    f32x4 v[PER_T];
#pragma unroll
    for (int k = 0; k < PER_T; ++k) v[k] = xin[tid + k * TPB];

#pragma unroll
    for (int k = 0; k < PER_T; ++k) {
      const int idx = tid + k * TPB;
      const int h = idx / WQ;           // 0..111
      const int wq = idx - h * WQ;      // 0..27
      const bool rokTop = (h < NH - 1); // include row i=0
      const bool rokBot = (h > 0);      // include row i=2
      const bool w0 = (wq == 0);        // elem 0 is w==0   -> exclude j=2
      const bool wL = (wq == WQ - 1);   // elem 3 is w==111 -> exclude j=0

      f32x4 res;
#pragma unroll
      for (int e = 0; e < 4; ++e) {
        const float vx = v[k][e];
        const bool exclJ2 = (e == 0) && w0;
        const bool exclJ0 = (e == 3) && wL;
        float s = 0.0f;
#pragma unroll
        for (int i = 0; i < 3; ++i) {
          const float m0 = fmaxf(vx, t[3 * i + 0]);
          const float m1 = fmaxf(vx, t[3 * i + 1]);
          const float m2 = fmaxf(vx, t[3 * i + 2]);
          float r = m1;
          r += exclJ0 ? 0.0f : m0;
          r += exclJ2 ? 0.0f : m2;
          const bool rok = (i == 0) ? rokTop : (i == 2) ? rokBot : true;
          s += rok ? r : 0.0f;
        }
        res[e] = s;
      }
      __builtin_nontemporal_store(res, &xout[idx]);
    }
  }
}

extern "C" void kernel_launch(void* const* d_in, const int* in_sizes, int n_in,
                              void* d_out, int out_size, void* d_ws, size_t ws_size,
                              hipStream_t stream) {
  const float* x = (const float*)d_in[0];    // (8,64,112,112) f32
  const float* thr = (const float*)d_in[1];  // (64,9) f32
  float* out = (float*)d_out;                // (8,64,112,112) f32

  convblock_ntrep_kernel<<<dim3(512), TPB, 0, stream>>>(x, thr, out);
}

// Round 10
// 11.685 us; speedup vs baseline: 5.6458x; 5.6458x over previous
//
#include <hip/hip_runtime.h>

// FINAL: out[n,c,h,w] = sum over valid (i,j) in 3x3 of max(x[n,c,h,w], thr[c,3i+j])
// valid: i=0 iff h<111, i=2 iff h>0 (i=1 always); j=0 iff w<111, j=2 iff w>0.
// (unfold -> max -> fold overlap-add collapses to a pure elementwise op.)
//
// Roofline status (measured, R5/R9 diagnostics):
//   - irreducible traffic 51.4 MB (25.7 read + 25.7 write)
//   - steady-state kernel time 8.04 us/pass = 6.39 TB/s demand BW
//     >= m13 copy ceiling (6.29 TB/s); L3 serves ~half the reads.
//   - single-launch dur_us ~11.8 = kernel 8.0 + fixed launch/replay overhead.
//   - nt stores: no steady-state traffic change (Case B), kept as harmless.
//
// Structure: one block per (n,c) plane -> thr loads stay scalar; 3136 float4
// = 448 threads x 7, all 7 loads issued before compute (MLP); branch-free
// border math via cndmask selects.

#define WQ 28
#define NH 112
#define PLANE_F4 (NH * WQ)   // 3136
#define TPB 448
#define PER_T 7

typedef float f32x4 __attribute__((ext_vector_type(4)));

__global__ __launch_bounds__(TPB) void convblock_kernel(
    const float* __restrict__ x, const float* __restrict__ thr,
    float* __restrict__ out) {
  const int plane = blockIdx.x;   // n*64 + c (block-uniform)
  const int c = plane & 63;

  float t[9];
#pragma unroll
  for (int k = 0; k < 9; ++k) t[k] = thr[c * 9 + k];

  const f32x4* __restrict__ xin =
      reinterpret_cast<const f32x4*>(x) + (size_t)plane * PLANE_F4;
  f32x4* __restrict__ xout =
      reinterpret_cast<f32x4*>(out) + (size_t)plane * PLANE_F4;

  const int tid = threadIdx.x;

  // All 7 loads in flight before any compute.
  f32x4 v[PER_T];
#pragma unroll
  for (int k = 0; k < PER_T; ++k) v[k] = xin[tid + k * TPB];

#pragma unroll
  for (int k = 0; k < PER_T; ++k) {
    const int idx = tid + k * TPB;
    const int h = idx / WQ;           // 0..111
    const int wq = idx - h * WQ;      // 0..27
    const bool rokTop = (h < NH - 1); // include row i=0
    const bool rokBot = (h > 0);      // include row i=2
    const bool w0 = (wq == 0);        // elem 0 is w==0   -> exclude j=2
    const bool wL = (wq == WQ - 1);   // elem 3 is w==111 -> exclude j=0

    f32x4 res;
#pragma unroll
    for (int e = 0; e < 4; ++e) {
      const float vx = v[k][e];
      const bool exclJ2 = (e == 0) && w0;
      const bool exclJ0 = (e == 3) && wL;
      float s = 0.0f;
#pragma unroll
      for (int i = 0; i < 3; ++i) {
        const float m0 = fmaxf(vx, t[3 * i + 0]);
        const float m1 = fmaxf(vx, t[3 * i + 1]);
        const float m2 = fmaxf(vx, t[3 * i + 2]);
        float r = m1;
        r += exclJ0 ? 0.0f : m0;
        r += exclJ2 ? 0.0f : m2;
        const bool rok = (i == 0) ? rokTop : (i == 2) ? rokBot : true;
        s += rok ? r : 0.0f;
      }
      res[e] = s;
    }
    __builtin_nontemporal_store(res, &xout[idx]);
  }
}

extern "C" void kernel_launch(void* const* d_in, const int* in_sizes, int n_in,
                              void* d_out, int out_size, void* d_ws, size_t ws_size,
                              hipStream_t stream) {
  const float* x = (const float*)d_in[0];    // (8,64,112,112) f32
  const float* thr = (const float*)d_in[1];  // (64,9) f32
  float* out = (float*)d_out;                // (8,64,112,112) f32

  convblock_kernel<<<dim3(8 * 64), TPB, 0, stream>>>(x, thr, out);
}